// Round 13
// baseline (90.296 us; speedup 1.0000x reference)
//
#include <hip/hip_runtime.h>

#define NB 8192
#define EPS_BN 1e-5f

// padded LDS index: +4 floats every 32 => stride-16B lane patterns are
// conflict-free while float4/float2 alignment is preserved (4 | pad).
#define PADX(i) ((i) + ((((i) >> 5)) << 2))

using bf16x8 = __attribute__((ext_vector_type(8))) __bf16;
using bf16x4 = __attribute__((ext_vector_type(4))) __bf16;
using f32x4  = __attribute__((ext_vector_type(4))) float;
using f32x2  = __attribute__((ext_vector_type(2))) float;
using u32x4  = __attribute__((ext_vector_type(4))) unsigned int;

// d_ws layout (float offsets relative to wsf = d_ws + 1MB):
//   0 wA1[64] | 64 bA1[8] | 80 wB2[640] | 720 bB2[16] | 736 wC3[1536] | 2272 bC3[32]
//   2560 wih_p | 4608 whh_p | 6656 fc1_p | 8704 fc2_p | 9728 fc3_p
//   9984 bfr_p | 10112 fc1b_p | 10176 fc2b_p | 10208 fc3b_p | 12288 spatial_bf16
#define WSF_OFF 262144
#define PK_WIH  2560
#define PK_WHH  4608
#define PK_FC1  6656
#define PK_FC2  8704
#define PK_FC3  9728
#define PK_BFR  9984
#define PK_B1   10112
#define PK_B2   10176
#define PK_B3   10208
#define PK_SPB  12288

__device__ inline unsigned pack_bf16(float a, float b) {
    union { __bf16 h; unsigned short u; } ca, cb;
    ca.h = (__bf16)a; cb.h = (__bf16)b;
    return (unsigned)ca.u | ((unsigned)cb.u << 16);
}

// ---------------------------------------------------------------------------
// Kernel 0: fold BN into conv weights + prepack lstm/fc fragments (UNCHANGED).
// ---------------------------------------------------------------------------
__global__ __launch_bounds__(256) void fold_kernel(
    const float* __restrict__ w1, const float* __restrict__ b1,
    const float* __restrict__ g1, const float* __restrict__ be1,
    const float* __restrict__ m1, const float* __restrict__ v1,
    const float* __restrict__ w2, const float* __restrict__ b2,
    const float* __restrict__ g2, const float* __restrict__ be2,
    const float* __restrict__ m2, const float* __restrict__ v2,
    const float* __restrict__ w3, const float* __restrict__ b3,
    const float* __restrict__ g3, const float* __restrict__ be3,
    const float* __restrict__ m3, const float* __restrict__ v3,
    const float* __restrict__ w_ih, const float* __restrict__ w_hh,
    const float* __restrict__ b_ih, const float* __restrict__ b_hh,
    const float* __restrict__ fc1w, const float* __restrict__ fc1b,
    const float* __restrict__ fc2w, const float* __restrict__ fc2b,
    const float* __restrict__ fc3w, const float* __restrict__ fc3b,
    float* __restrict__ wsf)
{
    int j = blockIdx.x * 256 + threadIdx.x;
    if (j < 64) {
        int k = j >> 3, c = j & 7;
        wsf[j] = (k < 7) ? w1[c * 7 + k] * (g1[c] * rsqrtf(v1[c] + EPS_BN)) : 0.f;
    } else if (j < 72) {
        int c = j - 64;
        float inv = g1[c] * rsqrtf(v1[c] + EPS_BN);
        wsf[j] = (b1[c] - m1[c]) * inv + be1[c];
    } else if (j >= 80 && j < 720) {
        int i = j - 80, c = i & 15, t = i >> 4, ci = t / 5, k = t - 5 * ci;
        wsf[j] = w2[(c * 8 + ci) * 5 + k] * (g2[c] * rsqrtf(v2[c] + EPS_BN));
    } else if (j >= 720 && j < 736) {
        int c = j - 720;
        float inv = g2[c] * rsqrtf(v2[c] + EPS_BN);
        wsf[j] = (b2[c] - m2[c]) * inv + be2[c];
    } else if (j >= 736 && j < 2272) {
        int i = j - 736, c = i & 31, t = i >> 5, ci = t / 3, k = t - 3 * ci;
        wsf[j] = w3[(c * 16 + ci) * 3 + k] * (g3[c] * rsqrtf(v3[c] + EPS_BN));
    } else if (j >= 2272 && j < 2304) {
        int c = j - 2272;
        float inv = g3[c] * rsqrtf(v3[c] + EPS_BN);
        wsf[j] = (b3[c] - m3[c]) * inv + be3[c];
    } else if (j >= 2560 && j < 3072) {
        int idx = j - 2560, T = idx >> 6, j6 = idx & 63, row = j6 & 15, q = j6 >> 4;
        const float* src = w_ih + (size_t)(16 * T + row) * 32 + 8 * q;
        unsigned* dst = (unsigned*)(wsf + PK_WIH) + (size_t)idx * 4;
        #pragma unroll
        for (int i = 0; i < 4; i++) dst[i] = pack_bf16(src[2 * i], src[2 * i + 1]);
    } else if (j >= 3072 && j < 3584) {
        int idx = j - 3072, T = idx >> 6, j6 = idx & 63, row = j6 & 15, q = j6 >> 4;
        const float* src = w_hh + (size_t)(16 * T + row) * 32 + 8 * q;
        unsigned* dst = (unsigned*)(wsf + PK_WHH) + (size_t)idx * 4;
        #pragma unroll
        for (int i = 0; i < 4; i++) dst[i] = pack_bf16(src[2 * i], src[2 * i + 1]);
    } else if (j >= 3584 && j < 4096) {
        int idx = j - 3584, f = idx >> 6, j6 = idx & 63, row = j6 & 15, q = j6 >> 4;
        int T = f >> 1, s = f & 1;
        const float* src = fc1w + (size_t)(16 * T + row) * 64 + 32 * s + 8 * q;
        unsigned* dst = (unsigned*)(wsf + PK_FC1) + (size_t)idx * 4;
        #pragma unroll
        for (int i = 0; i < 4; i++) dst[i] = pack_bf16(src[2 * i], src[2 * i + 1]);
    } else if (j >= 4096 && j < 4352) {
        int idx = j - 4096, f = idx >> 6, j6 = idx & 63, row = j6 & 15, q = j6 >> 4;
        int T = f >> 1, s = f & 1;
        const float* src = fc2w + (size_t)(16 * T + row) * 64 + 32 * s + 8 * q;
        unsigned* dst = (unsigned*)(wsf + PK_FC2) + (size_t)idx * 4;
        #pragma unroll
        for (int i = 0; i < 4; i++) dst[i] = pack_bf16(src[2 * i], src[2 * i + 1]);
    } else if (j >= 4352 && j < 4416) {
        int j6 = j - 4352, row = j6 & 15, q = j6 >> 4;
        const float* src = fc3w + (size_t)(row & 3) * 32 + 8 * q;
        unsigned* dst = (unsigned*)(wsf + PK_FC3) + (size_t)j6 * 4;
        #pragma unroll
        for (int i = 0; i < 4; i++) dst[i] = pack_bf16(src[2 * i], src[2 * i + 1]);
    } else if (j >= 4416 && j < 4448) {
        int idx = j - 4416, T = idx >> 2, q = idx & 3;
        #pragma unroll
        for (int i = 0; i < 4; i++)
            wsf[PK_BFR + idx * 4 + i] = b_ih[16 * T + 4 * q + i] + b_hh[16 * T + 4 * q + i];
    } else if (j >= 4448 && j < 4464) {
        int idx = j - 4448, T = idx >> 2, q = idx & 3;
        #pragma unroll
        for (int i = 0; i < 4; i++) wsf[PK_B1 + idx * 4 + i] = fc1b[16 * T + 4 * q + i];
    } else if (j >= 4464 && j < 4472) {
        int idx = j - 4464, T = idx >> 2, q = idx & 3;
        #pragma unroll
        for (int i = 0; i < 4; i++) wsf[PK_B2 + idx * 4 + i] = fc2b[16 * T + 4 * q + i];
    } else if (j == 4472) {
        #pragma unroll
        for (int i = 0; i < 4; i++) wsf[PK_B3 + i] = fc3b[i];
    }
}

// ---------------------------------------------------------------------------
// Kernel 1: conv stack + LIF (UNCHANGED from round 12).
// ---------------------------------------------------------------------------
__device__ inline f32x2 pkfma(f32x2 a, f32x2 b, f32x2 c) {
    return __builtin_elementwise_fma(a, b, c);
}

__device__ inline void conv1_pos(float* __restrict__ c1t,
                                 const float* __restrict__ xb,
                                 const float* __restrict__ wsf,
                                 int p, int idx)
{
    float4 gb = *reinterpret_cast<const float4*>(xb + 4 * p);
    float4 ga = make_float4(0.f, 0.f, 0.f, 0.f);
    if (p > 0) ga = *reinterpret_cast<const float4*>(xb + 4 * p - 4);
    float win[7] = {ga.y, ga.z, ga.w, gb.x, gb.y, gb.z, gb.w};
    #pragma unroll
    for (int cp = 0; cp < 4; cp++) {
        f32x2 acc = *reinterpret_cast<const f32x2*>(wsf + 64 + 2 * cp);
        #pragma unroll
        for (int k = 0; k < 7; k++) {
            f32x2 wv = *reinterpret_cast<const f32x2*>(wsf + k * 8 + 2 * cp);
            f32x2 sv = {win[k], win[k]};
            acc = pkfma(wv, sv, acc);
        }
        c1t[(2 * cp + 0) * 148 + PADX(idx)] = fmaxf(acc[0], 0.f);
        c1t[(2 * cp + 1) * 148 + PADX(idx)] = fmaxf(acc[1], 0.f);
    }
}

__global__ __launch_bounds__(256) void conv_lif_kernel(
    const float* __restrict__ x,
    float* __restrict__ wsf,
    float* __restrict__ spatial_out,
    unsigned int* __restrict__ spk)
{
    __shared__ alignas(16) float smem[4812];
    float* const c1b = smem;
    float* const c3b = smem;
    float* const c2b = smem + 2376;

    const int b0  = blockIdx.x * 2;
    const int tid = threadIdx.x;
    const float* xg0 = x + (size_t)b0 * 1024;
    const float* xg1 = x + (size_t)(b0 + 1) * 1024;

    #pragma unroll
    for (int h = 0; h < 2; h++) {
        {
            const int be = tid >> 7;
            const int lp = tid & 127;
            const float* xb = be ? xg1 : xg0;
            float* c1t = c1b + be * 1188;
            const int p = 126 * h + lp;
            conv1_pos(c1t, xb, wsf, p, p + 2 - 128 * h);
            if (h == 1 && lp == 0)
                conv1_pos(c1t, xb, wsf, 254, 128);
            if (h == 0 && lp < 2) {
                #pragma unroll
                for (int ch = 0; ch < 8; ch++) c1t[ch * 148 + lp] = 0.f;
            }
        }
        __syncthreads();

        {
            const int Pl = tid & 31;
            const int be = (tid >> 5) & 1;
            const int cq = __builtin_amdgcn_readfirstlane(tid >> 6) << 2;
            const int P  = 32 * h + Pl;
            const float* wB2 = wsf + 80;
            const float* bB2 = wsf + 720;
            f32x2 a01 = *reinterpret_cast<const f32x2*>(bB2 + cq);
            f32x2 a23 = *reinterpret_cast<const f32x2*>(bB2 + cq + 2);
            const float* c1t = c1b + be * 1188;
            float* c2t = c2b + be * 1220;
            if (h == 0 && Pl == 0) {
                #pragma unroll
                for (int j = 0; j < 4; j++) c2t[(cq + j) * 76] = 0.f;
            }
            #pragma unroll
            for (int ci = 0; ci < 8; ci++) {
                const float* row = c1t + ci * 148;
                float4 va = *reinterpret_cast<const float4*>(&row[PADX(4 * Pl)]);
                float  v4 = row[PADX(4 * Pl + 4)];
                float win[5] = {va.x, va.y, va.z, va.w, v4};
                #pragma unroll
                for (int k = 0; k < 5; k++) {
                    const float* wp = wB2 + (ci * 5 + k) * 16 + cq;
                    f32x2 sv = {win[k], win[k]};
                    a01 = pkfma(*reinterpret_cast<const f32x2*>(wp),     sv, a01);
                    a23 = pkfma(*reinterpret_cast<const f32x2*>(wp + 2), sv, a23);
                }
            }
            c2t[(cq + 0) * 76 + PADX(1 + P)] = fmaxf(a01[0], 0.f);
            c2t[(cq + 1) * 76 + PADX(1 + P)] = fmaxf(a01[1], 0.f);
            c2t[(cq + 2) * 76 + PADX(1 + P)] = fmaxf(a23[0], 0.f);
            c2t[(cq + 3) * 76 + PADX(1 + P)] = fmaxf(a23[1], 0.f);
        }
        __syncthreads();
    }

    {
        const int pl  = tid & 63;
        const int be  = pl >> 5;
        const int pos = pl & 31;
        const int cb  = __builtin_amdgcn_readfirstlane(tid >> 6) << 3;
        const float* wC3 = wsf + 736;
        const float* bC3 = wsf + 2272;
        f32x2 a01 = *reinterpret_cast<const f32x2*>(bC3 + cb);
        f32x2 a23 = *reinterpret_cast<const f32x2*>(bC3 + cb + 2);
        f32x2 a45 = *reinterpret_cast<const f32x2*>(bC3 + cb + 4);
        f32x2 a67 = *reinterpret_cast<const f32x2*>(bC3 + cb + 6);
        const float* c2t = c2b + be * 1220;
        #pragma unroll
        for (int ci = 0; ci < 16; ci++) {
            const float* row = c2t + ci * 76;
            float2 vab = *reinterpret_cast<const float2*>(&row[PADX(2 * pos)]);
            float  vc  = row[PADX(2 * pos + 2)];
            float win[3] = {vab.x, vab.y, vc};
            #pragma unroll
            for (int k = 0; k < 3; k++) {
                const float* wp = wC3 + (ci * 3 + k) * 32 + cb;
                f32x2 sv = {win[k], win[k]};
                a01 = pkfma(*reinterpret_cast<const f32x2*>(wp),     sv, a01);
                a23 = pkfma(*reinterpret_cast<const f32x2*>(wp + 2), sv, a23);
                a45 = pkfma(*reinterpret_cast<const f32x2*>(wp + 4), sv, a45);
                a67 = pkfma(*reinterpret_cast<const f32x2*>(wp + 6), sv, a67);
            }
        }
        float* c3t = c3b + be * 1060;
        c3t[(cb + 0) * 33 + pos] = fmaxf(a01[0], 0.f);
        c3t[(cb + 1) * 33 + pos] = fmaxf(a01[1], 0.f);
        c3t[(cb + 2) * 33 + pos] = fmaxf(a23[0], 0.f);
        c3t[(cb + 3) * 33 + pos] = fmaxf(a23[1], 0.f);
        c3t[(cb + 4) * 33 + pos] = fmaxf(a45[0], 0.f);
        c3t[(cb + 5) * 33 + pos] = fmaxf(a45[1], 0.f);
        c3t[(cb + 6) * 33 + pos] = fmaxf(a67[0], 0.f);
        c3t[(cb + 7) * 33 + pos] = fmaxf(a67[1], 0.f);
    }
    __syncthreads();

    if (tid < 64) {
        const int be = tid >> 5, ch = tid & 31;
        const float* c3t = c3b + be * 1060;
        float s = 0.f;
        #pragma unroll
        for (int t = 0; t < 32; t++) s += c3t[ch * 33 + t];
        float sv = s * 0.03125f;
        spatial_out[(size_t)(b0 + be) * 32 + ch] = sv;
        union { __bf16 h; unsigned short u; } cv;
        cv.h = (__bf16)sv;
        ((unsigned short*)(wsf + PK_SPB))[(size_t)(b0 + be) * 32 + ch] = cv.u;

        float mem = 0.f;
        #pragma unroll
        for (int t = 0; t < 32; t++) {
            mem = __fadd_rn(__fmul_rn(0.9f, mem), c3t[ch * 33 + t]);
            bool spike = mem > 0.5f;
            mem = spike ? 0.f : mem;
            unsigned long long msk = __ballot(spike);
            if (tid == 0) {
                spk[(size_t)b0 * 32 + t]      = (unsigned int)(msk & 0xffffffffull);
                spk[(size_t)b0 * 32 + 32 + t] = (unsigned int)(msk >> 32);
            }
        }
    }
}

// ---------------------------------------------------------------------------
// Kernel 2: MFMA-batched LSTM + FC head — TWO independent 16-batch tiles per
// wave (grid NB/32). Weights shared in VGPRs; the two tiles' MFMA and
// activation chains interleave to hide per-step latency within the wave
// (barrier-free). launch_bounds(64,1) lifts the VGPR cap (~230 needed).
// Per-tile arithmetic bit-identical to round 12.
// ---------------------------------------------------------------------------
__device__ inline float sigm(float x) {
    return __builtin_amdgcn_rcpf(1.f + __expf(-x));
}
__device__ inline float tanh_(float x) {
    return fmaf(2.f, __builtin_amdgcn_rcpf(1.f + __expf(-2.f * x)), -1.f);
}

#define BUILD_A1(a1, m, q) do {                                              \
    unsigned by_ = ((m) >> ((q) * 8)) & 0xFFu;                               \
    (a1).u[0] = ((by_ & 1u)        * 0x3F80u) | (((by_ >> 1) & 1u) * 0x3F800000u); \
    (a1).u[1] = (((by_ >> 2) & 1u) * 0x3F80u) | (((by_ >> 3) & 1u) * 0x3F800000u); \
    (a1).u[2] = (((by_ >> 4) & 1u) * 0x3F80u) | (((by_ >> 5) & 1u) * 0x3F800000u); \
    (a1).u[3] = (((by_ >> 6) & 1u) * 0x3F80u) | (((by_ >> 7) & 1u) * 0x3F800000u); \
} while (0)

__global__ __launch_bounds__(64, 1) void lstm_fc_mfma_kernel(
    const unsigned int* __restrict__ spk,   // [B][32]
    const float* __restrict__ wsf,          // prepacked weights + spatial_bf
    float* __restrict__ out0,               // [B][4]
    float* __restrict__ hlast_out)          // [B][32]
{
    const int l    = threadIdx.x;
    const int row  = l & 15;
    const int q    = l >> 4;
    const int base = blockIdx.x * 32;       // two tiles: base, base+16

    __shared__ unsigned int mlds[1024];     // [u][t][16]
    __shared__ __bf16 hlds[1280];           // [u][16][40]
    __shared__ __bf16 zlds[2304];           // [u][16][72]

    for (int i = l; i < 1024; i += 64) {
        int u = i >> 9, r = i & 511, j = r >> 5, t = r & 31;
        mlds[u * 512 + t * 16 + j] = spk[(size_t)(base + u * 16 + j) * 32 + t];
    }
    for (int i = l; i < 1280; i += 64) hlds[i] = (__bf16)0.f;

    union bc { u32x4 u; bf16x8 v; };
    const u32x4* wihp = (const u32x4*)(wsf + PK_WIH);
    const u32x4* whhp = (const u32x4*)(wsf + PK_WHH);

    bf16x8 wih[8], whh[8];
    f32x4  bfr[8];
    #pragma unroll
    for (int T = 0; T < 8; T++) {
        bc a; a.u = wihp[T * 64 + l]; wih[T] = a.v;
        bc b; b.u = whhp[T * 64 + l]; whh[T] = b.v;
        bfr[T] = *reinterpret_cast<const f32x4*>(wsf + PK_BFR + (T * 4 + q) * 4);
    }

    float cstA[8], hqA[8], cstB[8], hqB[8];
    #pragma unroll
    for (int i = 0; i < 8; i++) { cstA[i] = 0.f; hqA[i] = 0.f; cstB[i] = 0.f; hqB[i] = 0.f; }

    #pragma unroll 1
    for (int t = 0; t < 32; t++) {
        unsigned mA = mlds[t * 16 + row];
        unsigned mB = mlds[512 + t * 16 + row];
        union { bf16x8 v; unsigned u[4]; } a1A, a1B;
        BUILD_A1(a1A, mA, q);
        BUILD_A1(a1B, mB, q);
        bf16x8 a2A = *reinterpret_cast<bf16x8*>(&hlds[row * 40 + q * 8]);
        bf16x8 a2B = *reinterpret_cast<bf16x8*>(&hlds[640 + row * 40 + q * 8]);

        f32x4 accA[8], accB[8];
        #pragma unroll
        for (int T = 0; T < 8; T++) {
            accA[T] = __builtin_amdgcn_mfma_f32_16x16x32_bf16(wih[T], a1A.v, bfr[T], 0, 0, 0);
            accB[T] = __builtin_amdgcn_mfma_f32_16x16x32_bf16(wih[T], a1B.v, bfr[T], 0, 0, 0);
        }
        #pragma unroll
        for (int T = 0; T < 8; T++) {
            accA[T] = __builtin_amdgcn_mfma_f32_16x16x32_bf16(whh[T], a2A, accA[T], 0, 0, 0);
            accB[T] = __builtin_amdgcn_mfma_f32_16x16x32_bf16(whh[T], a2B, accB[T], 0, 0, 0);
        }

        #pragma unroll
        for (int j = 0; j < 4; j++) {
            {
                float iv = sigm(accA[0][j]);
                float fv = sigm(accA[2][j]);
                float gv = tanh_(accA[4][j]);
                float ov = sigm(accA[6][j]);
                cstA[j] = fmaf(fv, cstA[j], iv * gv);
                hqA[j]  = ov * tanh_(cstA[j]);
                float iv2 = sigm(accA[1][j]);
                float fv2 = sigm(accA[3][j]);
                float gv2 = tanh_(accA[5][j]);
                float ov2 = sigm(accA[7][j]);
                cstA[4 + j] = fmaf(fv2, cstA[4 + j], iv2 * gv2);
                hqA[4 + j]  = ov2 * tanh_(cstA[4 + j]);
            }
            {
                float iv = sigm(accB[0][j]);
                float fv = sigm(accB[2][j]);
                float gv = tanh_(accB[4][j]);
                float ov = sigm(accB[6][j]);
                cstB[j] = fmaf(fv, cstB[j], iv * gv);
                hqB[j]  = ov * tanh_(cstB[j]);
                float iv2 = sigm(accB[1][j]);
                float fv2 = sigm(accB[3][j]);
                float gv2 = tanh_(accB[5][j]);
                float ov2 = sigm(accB[7][j]);
                cstB[4 + j] = fmaf(fv2, cstB[4 + j], iv2 * gv2);
                hqB[4 + j]  = ov2 * tanh_(cstB[4 + j]);
            }
        }

        bf16x4 hv0A, hv1A, hv0B, hv1B;
        #pragma unroll
        for (int j = 0; j < 4; j++) {
            hv0A[j] = (__bf16)hqA[j]; hv1A[j] = (__bf16)hqA[4 + j];
            hv0B[j] = (__bf16)hqB[j]; hv1B[j] = (__bf16)hqB[4 + j];
        }
        *reinterpret_cast<bf16x4*>(&hlds[row * 40 + 4 * q])            = hv0A;
        *reinterpret_cast<bf16x4*>(&hlds[row * 40 + 16 + 4 * q])       = hv1A;
        *reinterpret_cast<bf16x4*>(&hlds[640 + row * 40 + 4 * q])      = hv0B;
        *reinterpret_cast<bf16x4*>(&hlds[640 + row * 40 + 16 + 4 * q]) = hv1B;
    }

    // ---- h_last outputs ----
    {
        f32x4 lo, hi;
        #pragma unroll
        for (int j = 0; j < 4; j++) { lo[j] = hqA[j]; hi[j] = hqA[4 + j]; }
        *reinterpret_cast<f32x4*>(hlast_out + (size_t)(base + row) * 32 + 4 * q)      = lo;
        *reinterpret_cast<f32x4*>(hlast_out + (size_t)(base + row) * 32 + 16 + 4 * q) = hi;
        #pragma unroll
        for (int j = 0; j < 4; j++) { lo[j] = hqB[j]; hi[j] = hqB[4 + j]; }
        *reinterpret_cast<f32x4*>(hlast_out + (size_t)(base + 16 + row) * 32 + 4 * q)      = lo;
        *reinterpret_cast<f32x4*>(hlast_out + (size_t)(base + 16 + row) * 32 + 16 + 4 * q) = hi;
    }

    // ---- FC head per tile (u is compile-time under unroll) ----
    const u32x4* fc1p = (const u32x4*)(wsf + PK_FC1);
    const u32x4* fc2p = (const u32x4*)(wsf + PK_FC2);
    #pragma unroll
    for (int u = 0; u < 2; u++) {
        __bf16* hl = hlds + u * 640;
        __bf16* zl = zlds + u * 1152;
        const int tb = base + u * 16;

        bf16x8 hf = *reinterpret_cast<bf16x8*>(&hl[row * 40 + 8 * q]);
        bf16x8 spf;
        {
            bc s_;
            s_.u = *reinterpret_cast<const u32x4*>(
                (const unsigned short*)(wsf + PK_SPB) + (size_t)(tb + row) * 32 + 8 * q);
            spf = s_.v;
        }

        #pragma unroll
        for (int T = 0; T < 4; T++) {
            bc x0_, x1_;
            x0_.u = fc1p[(T * 2 + 0) * 64 + l];
            x1_.u = fc1p[(T * 2 + 1) * 64 + l];
            f32x4 c = *reinterpret_cast<const f32x4*>(wsf + PK_B1 + (T * 4 + q) * 4);
            f32x4 a = __builtin_amdgcn_mfma_f32_16x16x32_bf16(x0_.v, hf,  c, 0, 0, 0);
            a       = __builtin_amdgcn_mfma_f32_16x16x32_bf16(x1_.v, spf, a, 0, 0, 0);
            bf16x4 zv;
            #pragma unroll
            for (int i = 0; i < 4; i++) zv[i] = (__bf16)fmaxf(a[i], 0.f);
            *reinterpret_cast<bf16x4*>(&zl[row * 72 + 16 * T + 4 * q]) = zv;
        }
        bf16x8 z1f0 = *reinterpret_cast<bf16x8*>(&zl[row * 72 + 8 * q]);
        bf16x8 z1f1 = *reinterpret_cast<bf16x8*>(&zl[row * 72 + 32 + 8 * q]);

        #pragma unroll
        for (int T = 0; T < 2; T++) {
            bc x0_, x1_;
            x0_.u = fc2p[(T * 2 + 0) * 64 + l];
            x1_.u = fc2p[(T * 2 + 1) * 64 + l];
            f32x4 c = *reinterpret_cast<const f32x4*>(wsf + PK_B2 + (T * 4 + q) * 4);
            f32x4 a = __builtin_amdgcn_mfma_f32_16x16x32_bf16(x0_.v, z1f0, c, 0, 0, 0);
            a       = __builtin_amdgcn_mfma_f32_16x16x32_bf16(x1_.v, z1f1, a, 0, 0, 0);
            bf16x4 zv;
            #pragma unroll
            for (int i = 0; i < 4; i++) zv[i] = (__bf16)fmaxf(a[i], 0.f);
            *reinterpret_cast<bf16x4*>(&hl[row * 40 + 16 * T + 4 * q]) = zv;
        }
        bf16x8 z2f = *reinterpret_cast<bf16x8*>(&hl[row * 40 + 8 * q]);

        {
            bc x3_;
            x3_.u = ((const u32x4*)(wsf + PK_FC3))[l];
            f32x4 c = *reinterpret_cast<const f32x4*>(wsf + PK_B3);
            f32x4 o = __builtin_amdgcn_mfma_f32_16x16x32_bf16(x3_.v, z2f, c, 0, 0, 0);
            if (l < 16)
                *reinterpret_cast<f32x4*>(out0 + (size_t)(tb + row) * 4) = o;
        }
    }
}

// ---------------------------------------------------------------------------
extern "C" void kernel_launch(void* const* d_in, const int* in_sizes, int n_in,
                              void* d_out, int out_size, void* d_ws, size_t ws_size,
                              hipStream_t stream) {
    const float* x    = (const float*)d_in[0];
    const float* w1   = (const float*)d_in[1];
    const float* b1   = (const float*)d_in[2];
    const float* g1   = (const float*)d_in[3];
    const float* be1  = (const float*)d_in[4];
    const float* m1   = (const float*)d_in[5];
    const float* v1   = (const float*)d_in[6];
    const float* w2   = (const float*)d_in[7];
    const float* b2   = (const float*)d_in[8];
    const float* g2   = (const float*)d_in[9];
    const float* be2  = (const float*)d_in[10];
    const float* m2   = (const float*)d_in[11];
    const float* v2   = (const float*)d_in[12];
    const float* w3   = (const float*)d_in[13];
    const float* b3   = (const float*)d_in[14];
    const float* g3   = (const float*)d_in[15];
    const float* be3  = (const float*)d_in[16];
    const float* m3   = (const float*)d_in[17];
    const float* v3   = (const float*)d_in[18];
    const float* w_ih = (const float*)d_in[19];
    const float* w_hh = (const float*)d_in[20];
    const float* b_ih = (const float*)d_in[21];
    const float* b_hh = (const float*)d_in[22];
    const float* fc1w = (const float*)d_in[23];
    const float* fc1b = (const float*)d_in[24];
    const float* fc2w = (const float*)d_in[25];
    const float* fc2b = (const float*)d_in[26];
    const float* fc3w = (const float*)d_in[27];
    const float* fc3b = (const float*)d_in[28];

    float* out0    = (float*)d_out;                 // [8192][4]
    float* spatial = out0 + (size_t)NB * 4;         // [8192][32]
    float* hlast   = spatial + (size_t)NB * 32;     // [8192][32]
    unsigned int* spk = (unsigned int*)d_ws;        // [8192][32] bitmasks
    float* wsf = (float*)d_ws + WSF_OFF;            // folded + prepacked weights

    hipLaunchKernelGGL(fold_kernel, dim3(18), dim3(256), 0, stream,
                       w1, b1, g1, be1, m1, v1,
                       w2, b2, g2, be2, m2, v2,
                       w3, b3, g3, be3, m3, v3,
                       w_ih, w_hh, b_ih, b_hh,
                       fc1w, fc1b, fc2w, fc2b, fc3w, fc3b, wsf);

    hipLaunchKernelGGL(conv_lif_kernel, dim3(NB / 2), dim3(256), 0, stream,
                       x, wsf, spatial, spk);

    hipLaunchKernelGGL(lstm_fc_mfma_kernel, dim3(NB / 32), dim3(64), 0, stream,
                       spk, wsf, out0, hlast);
}

// Round 14
// 67.744 us; speedup vs baseline: 1.3329x; 1.3329x over previous
//
#include <hip/hip_runtime.h>

#define NB 8192
#define EPS_BN 1e-5f

// padded LDS index: +4 floats every 32 => stride-16B lane patterns are
// conflict-free while float4/float2 alignment is preserved (4 | pad).
#define PADX(i) ((i) + ((((i) >> 5)) << 2))

using bf16x8 = __attribute__((ext_vector_type(8))) __bf16;
using bf16x4 = __attribute__((ext_vector_type(4))) __bf16;
using f32x4  = __attribute__((ext_vector_type(4))) float;
using f32x2  = __attribute__((ext_vector_type(2))) float;
using u32x4  = __attribute__((ext_vector_type(4))) unsigned int;

// d_ws layout (float offsets relative to wsf = d_ws + 1MB):
//   0 wA1[64] | 64 bA1[8] | 80 wB2[640] | 720 bB2[16] | 736 wC3[1536] | 2272 bC3[32]
//   2560 wih_p | 4608 whh_p | 6656 fc1_p | 8704 fc2_p | 9728 fc3_p
//   9984 bfr_p | 10112 fc1b_p | 10176 fc2b_p | 10208 fc3b_p | 12288 spatial_bf16
#define WSF_OFF 262144
#define PK_WIH  2560
#define PK_WHH  4608
#define PK_FC1  6656
#define PK_FC2  8704
#define PK_FC3  9728
#define PK_BFR  9984
#define PK_B1   10112
#define PK_B2   10176
#define PK_B3   10208
#define PK_SPB  12288

__device__ inline unsigned pack_bf16(float a, float b) {
    union { __bf16 h; unsigned short u; } ca, cb;
    ca.h = (__bf16)a; cb.h = (__bf16)b;
    return (unsigned)ca.u | ((unsigned)cb.u << 16);
}

// ---------------------------------------------------------------------------
// Kernel 0: fold BN into conv weights + prepack lstm/fc fragments (UNCHANGED
// from round 12).
// ---------------------------------------------------------------------------
__global__ __launch_bounds__(256) void fold_kernel(
    const float* __restrict__ w1, const float* __restrict__ b1,
    const float* __restrict__ g1, const float* __restrict__ be1,
    const float* __restrict__ m1, const float* __restrict__ v1,
    const float* __restrict__ w2, const float* __restrict__ b2,
    const float* __restrict__ g2, const float* __restrict__ be2,
    const float* __restrict__ m2, const float* __restrict__ v2,
    const float* __restrict__ w3, const float* __restrict__ b3,
    const float* __restrict__ g3, const float* __restrict__ be3,
    const float* __restrict__ m3, const float* __restrict__ v3,
    const float* __restrict__ w_ih, const float* __restrict__ w_hh,
    const float* __restrict__ b_ih, const float* __restrict__ b_hh,
    const float* __restrict__ fc1w, const float* __restrict__ fc1b,
    const float* __restrict__ fc2w, const float* __restrict__ fc2b,
    const float* __restrict__ fc3w, const float* __restrict__ fc3b,
    float* __restrict__ wsf)
{
    int j = blockIdx.x * 256 + threadIdx.x;
    if (j < 64) {
        int k = j >> 3, c = j & 7;
        wsf[j] = (k < 7) ? w1[c * 7 + k] * (g1[c] * rsqrtf(v1[c] + EPS_BN)) : 0.f;
    } else if (j < 72) {
        int c = j - 64;
        float inv = g1[c] * rsqrtf(v1[c] + EPS_BN);
        wsf[j] = (b1[c] - m1[c]) * inv + be1[c];
    } else if (j >= 80 && j < 720) {
        int i = j - 80, c = i & 15, t = i >> 4, ci = t / 5, k = t - 5 * ci;
        wsf[j] = w2[(c * 8 + ci) * 5 + k] * (g2[c] * rsqrtf(v2[c] + EPS_BN));
    } else if (j >= 720 && j < 736) {
        int c = j - 720;
        float inv = g2[c] * rsqrtf(v2[c] + EPS_BN);
        wsf[j] = (b2[c] - m2[c]) * inv + be2[c];
    } else if (j >= 736 && j < 2272) {
        int i = j - 736, c = i & 31, t = i >> 5, ci = t / 3, k = t - 3 * ci;
        wsf[j] = w3[(c * 16 + ci) * 3 + k] * (g3[c] * rsqrtf(v3[c] + EPS_BN));
    } else if (j >= 2272 && j < 2304) {
        int c = j - 2272;
        float inv = g3[c] * rsqrtf(v3[c] + EPS_BN);
        wsf[j] = (b3[c] - m3[c]) * inv + be3[c];
    } else if (j >= 2560 && j < 3072) {
        int idx = j - 2560, T = idx >> 6, j6 = idx & 63, row = j6 & 15, q = j6 >> 4;
        const float* src = w_ih + (size_t)(16 * T + row) * 32 + 8 * q;
        unsigned* dst = (unsigned*)(wsf + PK_WIH) + (size_t)idx * 4;
        #pragma unroll
        for (int i = 0; i < 4; i++) dst[i] = pack_bf16(src[2 * i], src[2 * i + 1]);
    } else if (j >= 3072 && j < 3584) {
        int idx = j - 3072, T = idx >> 6, j6 = idx & 63, row = j6 & 15, q = j6 >> 4;
        const float* src = w_hh + (size_t)(16 * T + row) * 32 + 8 * q;
        unsigned* dst = (unsigned*)(wsf + PK_WHH) + (size_t)idx * 4;
        #pragma unroll
        for (int i = 0; i < 4; i++) dst[i] = pack_bf16(src[2 * i], src[2 * i + 1]);
    } else if (j >= 3584 && j < 4096) {
        int idx = j - 3584, f = idx >> 6, j6 = idx & 63, row = j6 & 15, q = j6 >> 4;
        int T = f >> 1, s = f & 1;
        const float* src = fc1w + (size_t)(16 * T + row) * 64 + 32 * s + 8 * q;
        unsigned* dst = (unsigned*)(wsf + PK_FC1) + (size_t)idx * 4;
        #pragma unroll
        for (int i = 0; i < 4; i++) dst[i] = pack_bf16(src[2 * i], src[2 * i + 1]);
    } else if (j >= 4096 && j < 4352) {
        int idx = j - 4096, f = idx >> 6, j6 = idx & 63, row = j6 & 15, q = j6 >> 4;
        int T = f >> 1, s = f & 1;
        const float* src = fc2w + (size_t)(16 * T + row) * 64 + 32 * s + 8 * q;
        unsigned* dst = (unsigned*)(wsf + PK_FC2) + (size_t)idx * 4;
        #pragma unroll
        for (int i = 0; i < 4; i++) dst[i] = pack_bf16(src[2 * i], src[2 * i + 1]);
    } else if (j >= 4352 && j < 4416) {
        int j6 = j - 4352, row = j6 & 15, q = j6 >> 4;
        const float* src = fc3w + (size_t)(row & 3) * 32 + 8 * q;
        unsigned* dst = (unsigned*)(wsf + PK_FC3) + (size_t)j6 * 4;
        #pragma unroll
        for (int i = 0; i < 4; i++) dst[i] = pack_bf16(src[2 * i], src[2 * i + 1]);
    } else if (j >= 4416 && j < 4448) {
        int idx = j - 4416, T = idx >> 2, q = idx & 3;
        #pragma unroll
        for (int i = 0; i < 4; i++)
            wsf[PK_BFR + idx * 4 + i] = b_ih[16 * T + 4 * q + i] + b_hh[16 * T + 4 * q + i];
    } else if (j >= 4448 && j < 4464) {
        int idx = j - 4448, T = idx >> 2, q = idx & 3;
        #pragma unroll
        for (int i = 0; i < 4; i++) wsf[PK_B1 + idx * 4 + i] = fc1b[16 * T + 4 * q + i];
    } else if (j >= 4464 && j < 4472) {
        int idx = j - 4464, T = idx >> 2, q = idx & 3;
        #pragma unroll
        for (int i = 0; i < 4; i++) wsf[PK_B2 + idx * 4 + i] = fc2b[16 * T + 4 * q + i];
    } else if (j == 4472) {
        #pragma unroll
        for (int i = 0; i < 4; i++) wsf[PK_B3 + i] = fc3b[i];
    }
}

// ---------------------------------------------------------------------------
// Kernel 1: conv stack + LIF (UNCHANGED from round 12).
// ---------------------------------------------------------------------------
__device__ inline f32x2 pkfma(f32x2 a, f32x2 b, f32x2 c) {
    return __builtin_elementwise_fma(a, b, c);
}

__device__ inline void conv1_pos(float* __restrict__ c1t,
                                 const float* __restrict__ xb,
                                 const float* __restrict__ wsf,
                                 int p, int idx)
{
    float4 gb = *reinterpret_cast<const float4*>(xb + 4 * p);
    float4 ga = make_float4(0.f, 0.f, 0.f, 0.f);
    if (p > 0) ga = *reinterpret_cast<const float4*>(xb + 4 * p - 4);
    float win[7] = {ga.y, ga.z, ga.w, gb.x, gb.y, gb.z, gb.w};
    #pragma unroll
    for (int cp = 0; cp < 4; cp++) {
        f32x2 acc = *reinterpret_cast<const f32x2*>(wsf + 64 + 2 * cp);
        #pragma unroll
        for (int k = 0; k < 7; k++) {
            f32x2 wv = *reinterpret_cast<const f32x2*>(wsf + k * 8 + 2 * cp);
            f32x2 sv = {win[k], win[k]};
            acc = pkfma(wv, sv, acc);
        }
        c1t[(2 * cp + 0) * 148 + PADX(idx)] = fmaxf(acc[0], 0.f);
        c1t[(2 * cp + 1) * 148 + PADX(idx)] = fmaxf(acc[1], 0.f);
    }
}

__global__ __launch_bounds__(256) void conv_lif_kernel(
    const float* __restrict__ x,
    float* __restrict__ wsf,
    float* __restrict__ spatial_out,
    unsigned int* __restrict__ spk)
{
    __shared__ alignas(16) float smem[4812];
    float* const c1b = smem;
    float* const c3b = smem;
    float* const c2b = smem + 2376;

    const int b0  = blockIdx.x * 2;
    const int tid = threadIdx.x;
    const float* xg0 = x + (size_t)b0 * 1024;
    const float* xg1 = x + (size_t)(b0 + 1) * 1024;

    #pragma unroll
    for (int h = 0; h < 2; h++) {
        {
            const int be = tid >> 7;
            const int lp = tid & 127;
            const float* xb = be ? xg1 : xg0;
            float* c1t = c1b + be * 1188;
            const int p = 126 * h + lp;
            conv1_pos(c1t, xb, wsf, p, p + 2 - 128 * h);
            if (h == 1 && lp == 0)
                conv1_pos(c1t, xb, wsf, 254, 128);
            if (h == 0 && lp < 2) {
                #pragma unroll
                for (int ch = 0; ch < 8; ch++) c1t[ch * 148 + lp] = 0.f;
            }
        }
        __syncthreads();

        {
            const int Pl = tid & 31;
            const int be = (tid >> 5) & 1;
            const int cq = __builtin_amdgcn_readfirstlane(tid >> 6) << 2;
            const int P  = 32 * h + Pl;
            const float* wB2 = wsf + 80;
            const float* bB2 = wsf + 720;
            f32x2 a01 = *reinterpret_cast<const f32x2*>(bB2 + cq);
            f32x2 a23 = *reinterpret_cast<const f32x2*>(bB2 + cq + 2);
            const float* c1t = c1b + be * 1188;
            float* c2t = c2b + be * 1220;
            if (h == 0 && Pl == 0) {
                #pragma unroll
                for (int j = 0; j < 4; j++) c2t[(cq + j) * 76] = 0.f;
            }
            #pragma unroll
            for (int ci = 0; ci < 8; ci++) {
                const float* row = c1t + ci * 148;
                float4 va = *reinterpret_cast<const float4*>(&row[PADX(4 * Pl)]);
                float  v4 = row[PADX(4 * Pl + 4)];
                float win[5] = {va.x, va.y, va.z, va.w, v4};
                #pragma unroll
                for (int k = 0; k < 5; k++) {
                    const float* wp = wB2 + (ci * 5 + k) * 16 + cq;
                    f32x2 sv = {win[k], win[k]};
                    a01 = pkfma(*reinterpret_cast<const f32x2*>(wp),     sv, a01);
                    a23 = pkfma(*reinterpret_cast<const f32x2*>(wp + 2), sv, a23);
                }
            }
            c2t[(cq + 0) * 76 + PADX(1 + P)] = fmaxf(a01[0], 0.f);
            c2t[(cq + 1) * 76 + PADX(1 + P)] = fmaxf(a01[1], 0.f);
            c2t[(cq + 2) * 76 + PADX(1 + P)] = fmaxf(a23[0], 0.f);
            c2t[(cq + 3) * 76 + PADX(1 + P)] = fmaxf(a23[1], 0.f);
        }
        __syncthreads();
    }

    {
        const int pl  = tid & 63;
        const int be  = pl >> 5;
        const int pos = pl & 31;
        const int cb  = __builtin_amdgcn_readfirstlane(tid >> 6) << 3;
        const float* wC3 = wsf + 736;
        const float* bC3 = wsf + 2272;
        f32x2 a01 = *reinterpret_cast<const f32x2*>(bC3 + cb);
        f32x2 a23 = *reinterpret_cast<const f32x2*>(bC3 + cb + 2);
        f32x2 a45 = *reinterpret_cast<const f32x2*>(bC3 + cb + 4);
        f32x2 a67 = *reinterpret_cast<const f32x2*>(bC3 + cb + 6);
        const float* c2t = c2b + be * 1220;
        #pragma unroll
        for (int ci = 0; ci < 16; ci++) {
            const float* row = c2t + ci * 76;
            float2 vab = *reinterpret_cast<const float2*>(&row[PADX(2 * pos)]);
            float  vc  = row[PADX(2 * pos + 2)];
            float win[3] = {vab.x, vab.y, vc};
            #pragma unroll
            for (int k = 0; k < 3; k++) {
                const float* wp = wC3 + (ci * 3 + k) * 32 + cb;
                f32x2 sv = {win[k], win[k]};
                a01 = pkfma(*reinterpret_cast<const f32x2*>(wp),     sv, a01);
                a23 = pkfma(*reinterpret_cast<const f32x2*>(wp + 2), sv, a23);
                a45 = pkfma(*reinterpret_cast<const f32x2*>(wp + 4), sv, a45);
                a67 = pkfma(*reinterpret_cast<const f32x2*>(wp + 6), sv, a67);
            }
        }
        float* c3t = c3b + be * 1060;
        c3t[(cb + 0) * 33 + pos] = fmaxf(a01[0], 0.f);
        c3t[(cb + 1) * 33 + pos] = fmaxf(a01[1], 0.f);
        c3t[(cb + 2) * 33 + pos] = fmaxf(a23[0], 0.f);
        c3t[(cb + 3) * 33 + pos] = fmaxf(a23[1], 0.f);
        c3t[(cb + 4) * 33 + pos] = fmaxf(a45[0], 0.f);
        c3t[(cb + 5) * 33 + pos] = fmaxf(a45[1], 0.f);
        c3t[(cb + 6) * 33 + pos] = fmaxf(a67[0], 0.f);
        c3t[(cb + 7) * 33 + pos] = fmaxf(a67[1], 0.f);
    }
    __syncthreads();

    if (tid < 64) {
        const int be = tid >> 5, ch = tid & 31;
        const float* c3t = c3b + be * 1060;
        float s = 0.f;
        #pragma unroll
        for (int t = 0; t < 32; t++) s += c3t[ch * 33 + t];
        float sv = s * 0.03125f;
        spatial_out[(size_t)(b0 + be) * 32 + ch] = sv;
        union { __bf16 h; unsigned short u; } cv;
        cv.h = (__bf16)sv;
        ((unsigned short*)(wsf + PK_SPB))[(size_t)(b0 + be) * 32 + ch] = cv.u;

        float mem = 0.f;
        #pragma unroll
        for (int t = 0; t < 32; t++) {
            mem = __fadd_rn(__fmul_rn(0.9f, mem), c3t[ch * 33 + t]);
            bool spike = mem > 0.5f;
            mem = spike ? 0.f : mem;
            unsigned long long msk = __ballot(spike);
            if (tid == 0) {
                spk[(size_t)b0 * 32 + t]      = (unsigned int)(msk & 0xffffffffull);
                spk[(size_t)b0 * 32 + 32 + t] = (unsigned int)(msk >> 32);
            }
        }
    }
}

// ---------------------------------------------------------------------------
// Kernel 2: MFMA-batched LSTM + FC head — TWO waves per block, DOUBLE-BUFFERED
// h => ONE barrier per step. Wave w owns gate-tiles {w,2+w,4+w,6+w} (channels
// 16w..16w+15 of each gate; r9-verified arithmetic). Reads from hdb[cur],
// writes to hdb[cur^1], barrier, swap: reads-before-barrier and
// writes-after-barrier never touch the same buffer. 1024 waves = full SIMD
// coverage with half the transcendental work per wave. Prepacked fragment
// loads (r12). Per-output arithmetic bit-identical to round 12.
// ---------------------------------------------------------------------------
__device__ inline float sigm(float x) {
    return __builtin_amdgcn_rcpf(1.f + __expf(-x));
}
__device__ inline float tanh_(float x) {
    return fmaf(2.f, __builtin_amdgcn_rcpf(1.f + __expf(-2.f * x)), -1.f);
}

__global__ __launch_bounds__(128, 2) void lstm_fc_mfma_kernel(
    const unsigned int* __restrict__ spk,   // [B][32]
    const float* __restrict__ wsf,          // prepacked weights + spatial_bf
    float* __restrict__ out0,               // [B][4]
    float* __restrict__ hlast_out)          // [B][32]
{
    const int ltid = threadIdx.x;
    const int l    = ltid & 63;
    const int w    = ltid >> 6;             // wave 0/1
    const int row  = l & 15;                // batch-within-tile
    const int q    = l >> 4;                // k-group 0..3
    const int base = blockIdx.x * 16;

    __shared__ unsigned int mlds[512];           // [t][16]
    __shared__ alignas(16) __bf16 hdb[2][640];   // double-buffered [16][40]
    __shared__ alignas(16) __bf16 zlds[1152];    // [16][72]

    for (int i = ltid; i < 512; i += 128) {
        int j = i >> 5, t = i & 31;
        mlds[t * 16 + j] = spk[(size_t)(base + j) * 32 + t];
    }
    for (int i = ltid; i < 640; i += 128) hdb[0][i] = (__bf16)0.f;

    union bc { u32x4 u; bf16x8 v; };
    const u32x4* wihp = (const u32x4*)(wsf + PK_WIH);
    const u32x4* whhp = (const u32x4*)(wsf + PK_WHH);

    // wave w: tiles T = 2g + w, g = gate (i,f,g,o) -> channels 16w + 4q + j
    bf16x8 wih[4], whh[4];
    f32x4  bfr[4];
    #pragma unroll
    for (int g = 0; g < 4; g++) {
        const int T = 2 * g + w;
        bc a; a.u = wihp[T * 64 + l]; wih[g] = a.v;
        bc b; b.u = whhp[T * 64 + l]; whh[g] = b.v;
        bfr[g] = *reinterpret_cast<const f32x4*>(wsf + PK_BFR + (T * 4 + q) * 4);
    }

    float cst[4], hq[4];
    #pragma unroll
    for (int i = 0; i < 4; i++) { cst[i] = 0.f; hq[i] = 0.f; }
    __syncthreads();                        // mlds + hdb[0] ready

    int cur = 0;
    #pragma unroll 1
    for (int t = 0; t < 32; t++) {
        unsigned int m  = mlds[t * 16 + row];
        unsigned int by = (m >> (q * 8)) & 0xFFu;
        union { bf16x8 v; unsigned int u[4]; } a1;
        a1.u[0] = ((by & 1u)        * 0x3F80u) | (((by >> 1) & 1u) * 0x3F800000u);
        a1.u[1] = (((by >> 2) & 1u) * 0x3F80u) | (((by >> 3) & 1u) * 0x3F800000u);
        a1.u[2] = (((by >> 4) & 1u) * 0x3F80u) | (((by >> 5) & 1u) * 0x3F800000u);
        a1.u[3] = (((by >> 6) & 1u) * 0x3F80u) | (((by >> 7) & 1u) * 0x3F800000u);
        bf16x8 a2 = *reinterpret_cast<bf16x8*>(&hdb[cur][row * 40 + q * 8]);

        f32x4 acc[4];
        #pragma unroll
        for (int g = 0; g < 4; g++) {
            acc[g] = __builtin_amdgcn_mfma_f32_16x16x32_bf16(wih[g], a1.v, bfr[g], 0, 0, 0);
            acc[g] = __builtin_amdgcn_mfma_f32_16x16x32_bf16(whh[g], a2,   acc[g], 0, 0, 0);
        }

        #pragma unroll
        for (int j = 0; j < 4; j++) {
            float iv = sigm(acc[0][j]);
            float fv = sigm(acc[1][j]);
            float gv = tanh_(acc[2][j]);
            float ov = sigm(acc[3][j]);
            cst[j] = fmaf(fv, cst[j], iv * gv);
            hq[j]  = ov * tanh_(cst[j]);
        }

        bf16x4 hv;
        #pragma unroll
        for (int j = 0; j < 4; j++) hv[j] = (__bf16)hq[j];
        *reinterpret_cast<bf16x4*>(&hdb[cur ^ 1][row * 40 + 16 * w + 4 * q]) = hv;
        __syncthreads();                    // writes of this step done; next
        cur ^= 1;                           // step writes the other buffer
    }

    // ---- h_last output (fp32, from registers) ----
    {
        f32x4 lo;
        #pragma unroll
        for (int j = 0; j < 4; j++) lo[j] = hq[j];
        *reinterpret_cast<f32x4*>(hlast_out + (size_t)(base + row) * 32 + 16 * w + 4 * q) = lo;
    }

    // ---- FC head (tiles split across the two waves) ----
    bf16x8 hf = *reinterpret_cast<bf16x8*>(&hdb[cur][row * 40 + 8 * q]);
    bf16x8 spf;
    {
        bc s_;
        s_.u = *reinterpret_cast<const u32x4*>(
            (const unsigned short*)(wsf + PK_SPB) + (size_t)(base + row) * 32 + 8 * q);
        spf = s_.v;
    }

    // fc1: 4 tiles; wave w does T = {w, 2+w}
    const u32x4* fc1p = (const u32x4*)(wsf + PK_FC1);
    #pragma unroll
    for (int g = 0; g < 2; g++) {
        const int T = 2 * g + w;
        bc x0_, x1_;
        x0_.u = fc1p[(T * 2 + 0) * 64 + l];
        x1_.u = fc1p[(T * 2 + 1) * 64 + l];
        f32x4 c = *reinterpret_cast<const f32x4*>(wsf + PK_B1 + (T * 4 + q) * 4);
        f32x4 a = __builtin_amdgcn_mfma_f32_16x16x32_bf16(x0_.v, hf,  c, 0, 0, 0);
        a       = __builtin_amdgcn_mfma_f32_16x16x32_bf16(x1_.v, spf, a, 0, 0, 0);
        bf16x4 zv;
        #pragma unroll
        for (int i = 0; i < 4; i++) zv[i] = (__bf16)fmaxf(a[i], 0.f);
        *reinterpret_cast<bf16x4*>(&zlds[row * 72 + 16 * T + 4 * q]) = zv;
    }
    __syncthreads();
    bf16x8 z1f0 = *reinterpret_cast<bf16x8*>(&zlds[row * 72 + 8 * q]);
    bf16x8 z1f1 = *reinterpret_cast<bf16x8*>(&zlds[row * 72 + 32 + 8 * q]);

    // fc2: 2 tiles; wave w does tile w; result into dead h buffer
    const u32x4* fc2p = (const u32x4*)(wsf + PK_FC2);
    {
        const int T = w;
        bc x0_, x1_;
        x0_.u = fc2p[(T * 2 + 0) * 64 + l];
        x1_.u = fc2p[(T * 2 + 1) * 64 + l];
        f32x4 c = *reinterpret_cast<const f32x4*>(wsf + PK_B2 + (T * 4 + q) * 4);
        f32x4 a = __builtin_amdgcn_mfma_f32_16x16x32_bf16(x0_.v, z1f0, c, 0, 0, 0);
        a       = __builtin_amdgcn_mfma_f32_16x16x32_bf16(x1_.v, z1f1, a, 0, 0, 0);
        bf16x4 zv;
        #pragma unroll
        for (int i = 0; i < 4; i++) zv[i] = (__bf16)fmaxf(a[i], 0.f);
        *reinterpret_cast<bf16x4*>(&hdb[cur ^ 1][row * 40 + 16 * T + 4 * q]) = zv;
    }
    __syncthreads();

    // fc3: wave 0 only
    if (w == 0) {
        bf16x8 z2f = *reinterpret_cast<bf16x8*>(&hdb[cur ^ 1][row * 40 + 8 * q]);
        bc x3_;
        x3_.u = ((const u32x4*)(wsf + PK_FC3))[l];
        f32x4 c = *reinterpret_cast<const f32x4*>(wsf + PK_B3);
        f32x4 o = __builtin_amdgcn_mfma_f32_16x16x32_bf16(x3_.v, z2f, c, 0, 0, 0);
        if (l < 16)
            *reinterpret_cast<f32x4*>(out0 + (size_t)(base + row) * 4) = o;
    }
}

// ---------------------------------------------------------------------------
extern "C" void kernel_launch(void* const* d_in, const int* in_sizes, int n_in,
                              void* d_out, int out_size, void* d_ws, size_t ws_size,
                              hipStream_t stream) {
    const float* x    = (const float*)d_in[0];
    const float* w1   = (const float*)d_in[1];
    const float* b1   = (const float*)d_in[2];
    const float* g1   = (const float*)d_in[3];
    const float* be1  = (const float*)d_in[4];
    const float* m1   = (const float*)d_in[5];
    const float* v1   = (const float*)d_in[6];
    const float* w2   = (const float*)d_in[7];
    const float* b2   = (const float*)d_in[8];
    const float* g2   = (const float*)d_in[9];
    const float* be2  = (const float*)d_in[10];
    const float* m2   = (const float*)d_in[11];
    const float* v2   = (const float*)d_in[12];
    const float* w3   = (const float*)d_in[13];
    const float* b3   = (const float*)d_in[14];
    const float* g3   = (const float*)d_in[15];
    const float* be3  = (const float*)d_in[16];
    const float* m3   = (const float*)d_in[17];
    const float* v3   = (const float*)d_in[18];
    const float* w_ih = (const float*)d_in[19];
    const float* w_hh = (const float*)d_in[20];
    const float* b_ih = (const float*)d_in[21];
    const float* b_hh = (const float*)d_in[22];
    const float* fc1w = (const float*)d_in[23];
    const float* fc1b = (const float*)d_in[24];
    const float* fc2w = (const float*)d_in[25];
    const float* fc2b = (const float*)d_in[26];
    const float* fc3w = (const float*)d_in[27];
    const float* fc3b = (const float*)d_in[28];

    float* out0    = (float*)d_out;                 // [8192][4]
    float* spatial = out0 + (size_t)NB * 4;         // [8192][32]
    float* hlast   = spatial + (size_t)NB * 32;     // [8192][32]
    unsigned int* spk = (unsigned int*)d_ws;        // [8192][32] bitmasks
    float* wsf = (float*)d_ws + WSF_OFF;            // folded + prepacked weights

    hipLaunchKernelGGL(fold_kernel, dim3(18), dim3(256), 0, stream,
                       w1, b1, g1, be1, m1, v1,
                       w2, b2, g2, be2, m2, v2,
                       w3, b3, g3, be3, m3, v3,
                       w_ih, w_hh, b_ih, b_hh,
                       fc1w, fc1b, fc2w, fc2b, fc3w, fc3b, wsf);

    hipLaunchKernelGGL(conv_lif_kernel, dim3(NB / 2), dim3(256), 0, stream,
                       x, wsf, spatial, spk);

    hipLaunchKernelGGL(lstm_fc_mfma_kernel, dim3(NB / 16), dim3(128), 0, stream,
                       spk, wsf, out0, hlast);
}

// Round 15
// 63.021 us; speedup vs baseline: 1.4328x; 1.0749x over previous
//
#include <hip/hip_runtime.h>

#define NB 8192
#define EPS_BN 1e-5f

// padded LDS index: +4 floats every 32 => stride-16B lane patterns are
// conflict-free while float4/float2 alignment is preserved (4 | pad).
#define PADX(i) ((i) + ((((i) >> 5)) << 2))

using bf16x8 = __attribute__((ext_vector_type(8))) __bf16;
using bf16x4 = __attribute__((ext_vector_type(4))) __bf16;
using f32x4  = __attribute__((ext_vector_type(4))) float;
using f32x2  = __attribute__((ext_vector_type(2))) float;
using u32x4  = __attribute__((ext_vector_type(4))) unsigned int;

// d_ws layout (float offsets relative to wsf = d_ws + 1MB):
//   0 wA1[64] | 64 bA1[8] | 80 wB2[640] | 720 bB2[16] | 736 wC3[1536] | 2272 bC3[32]
//   2560 wih_p | 4608 whh_p | 6656 fc1_p | 8704 fc2_p | 9728 fc3_p
//   9984 bfr_p | 10112 fc1b_p | 10176 fc2b_p | 10208 fc3b_p | 12288 spatial_bf16
#define WSF_OFF 262144
#define PK_WIH  2560
#define PK_WHH  4608
#define PK_FC1  6656
#define PK_FC2  8704
#define PK_FC3  9728
#define PK_BFR  9984
#define PK_B1   10112
#define PK_B2   10176
#define PK_B3   10208
#define PK_SPB  12288

__device__ inline unsigned pack_bf16(float a, float b) {
    union { __bf16 h; unsigned short u; } ca, cb;
    ca.h = (__bf16)a; cb.h = (__bf16)b;
    return (unsigned)ca.u | ((unsigned)cb.u << 16);
}

// ---------------------------------------------------------------------------
// Kernel 0: fold BN into conv weights + prepack lstm/fc fragments (UNCHANGED
// from round 12).
// ---------------------------------------------------------------------------
__global__ __launch_bounds__(256) void fold_kernel(
    const float* __restrict__ w1, const float* __restrict__ b1,
    const float* __restrict__ g1, const float* __restrict__ be1,
    const float* __restrict__ m1, const float* __restrict__ v1,
    const float* __restrict__ w2, const float* __restrict__ b2,
    const float* __restrict__ g2, const float* __restrict__ be2,
    const float* __restrict__ m2, const float* __restrict__ v2,
    const float* __restrict__ w3, const float* __restrict__ b3,
    const float* __restrict__ g3, const float* __restrict__ be3,
    const float* __restrict__ m3, const float* __restrict__ v3,
    const float* __restrict__ w_ih, const float* __restrict__ w_hh,
    const float* __restrict__ b_ih, const float* __restrict__ b_hh,
    const float* __restrict__ fc1w, const float* __restrict__ fc1b,
    const float* __restrict__ fc2w, const float* __restrict__ fc2b,
    const float* __restrict__ fc3w, const float* __restrict__ fc3b,
    float* __restrict__ wsf)
{
    int j = blockIdx.x * 256 + threadIdx.x;
    if (j < 64) {
        int k = j >> 3, c = j & 7;
        wsf[j] = (k < 7) ? w1[c * 7 + k] * (g1[c] * rsqrtf(v1[c] + EPS_BN)) : 0.f;
    } else if (j < 72) {
        int c = j - 64;
        float inv = g1[c] * rsqrtf(v1[c] + EPS_BN);
        wsf[j] = (b1[c] - m1[c]) * inv + be1[c];
    } else if (j >= 80 && j < 720) {
        int i = j - 80, c = i & 15, t = i >> 4, ci = t / 5, k = t - 5 * ci;
        wsf[j] = w2[(c * 8 + ci) * 5 + k] * (g2[c] * rsqrtf(v2[c] + EPS_BN));
    } else if (j >= 720 && j < 736) {
        int c = j - 720;
        float inv = g2[c] * rsqrtf(v2[c] + EPS_BN);
        wsf[j] = (b2[c] - m2[c]) * inv + be2[c];
    } else if (j >= 736 && j < 2272) {
        int i = j - 736, c = i & 31, t = i >> 5, ci = t / 3, k = t - 3 * ci;
        wsf[j] = w3[(c * 16 + ci) * 3 + k] * (g3[c] * rsqrtf(v3[c] + EPS_BN));
    } else if (j >= 2272 && j < 2304) {
        int c = j - 2272;
        float inv = g3[c] * rsqrtf(v3[c] + EPS_BN);
        wsf[j] = (b3[c] - m3[c]) * inv + be3[c];
    } else if (j >= 2560 && j < 3072) {
        int idx = j - 2560, T = idx >> 6, j6 = idx & 63, row = j6 & 15, q = j6 >> 4;
        const float* src = w_ih + (size_t)(16 * T + row) * 32 + 8 * q;
        unsigned* dst = (unsigned*)(wsf + PK_WIH) + (size_t)idx * 4;
        #pragma unroll
        for (int i = 0; i < 4; i++) dst[i] = pack_bf16(src[2 * i], src[2 * i + 1]);
    } else if (j >= 3072 && j < 3584) {
        int idx = j - 3072, T = idx >> 6, j6 = idx & 63, row = j6 & 15, q = j6 >> 4;
        const float* src = w_hh + (size_t)(16 * T + row) * 32 + 8 * q;
        unsigned* dst = (unsigned*)(wsf + PK_WHH) + (size_t)idx * 4;
        #pragma unroll
        for (int i = 0; i < 4; i++) dst[i] = pack_bf16(src[2 * i], src[2 * i + 1]);
    } else if (j >= 3584 && j < 4096) {
        int idx = j - 3584, f = idx >> 6, j6 = idx & 63, row = j6 & 15, q = j6 >> 4;
        int T = f >> 1, s = f & 1;
        const float* src = fc1w + (size_t)(16 * T + row) * 64 + 32 * s + 8 * q;
        unsigned* dst = (unsigned*)(wsf + PK_FC1) + (size_t)idx * 4;
        #pragma unroll
        for (int i = 0; i < 4; i++) dst[i] = pack_bf16(src[2 * i], src[2 * i + 1]);
    } else if (j >= 4096 && j < 4352) {
        int idx = j - 4096, f = idx >> 6, j6 = idx & 63, row = j6 & 15, q = j6 >> 4;
        int T = f >> 1, s = f & 1;
        const float* src = fc2w + (size_t)(16 * T + row) * 64 + 32 * s + 8 * q;
        unsigned* dst = (unsigned*)(wsf + PK_FC2) + (size_t)idx * 4;
        #pragma unroll
        for (int i = 0; i < 4; i++) dst[i] = pack_bf16(src[2 * i], src[2 * i + 1]);
    } else if (j >= 4352 && j < 4416) {
        int j6 = j - 4352, row = j6 & 15, q = j6 >> 4;
        const float* src = fc3w + (size_t)(row & 3) * 32 + 8 * q;
        unsigned* dst = (unsigned*)(wsf + PK_FC3) + (size_t)j6 * 4;
        #pragma unroll
        for (int i = 0; i < 4; i++) dst[i] = pack_bf16(src[2 * i], src[2 * i + 1]);
    } else if (j >= 4416 && j < 4448) {
        int idx = j - 4416, T = idx >> 2, q = idx & 3;
        #pragma unroll
        for (int i = 0; i < 4; i++)
            wsf[PK_BFR + idx * 4 + i] = b_ih[16 * T + 4 * q + i] + b_hh[16 * T + 4 * q + i];
    } else if (j >= 4448 && j < 4464) {
        int idx = j - 4448, T = idx >> 2, q = idx & 3;
        #pragma unroll
        for (int i = 0; i < 4; i++) wsf[PK_B1 + idx * 4 + i] = fc1b[16 * T + 4 * q + i];
    } else if (j >= 4464 && j < 4472) {
        int idx = j - 4464, T = idx >> 2, q = idx & 3;
        #pragma unroll
        for (int i = 0; i < 4; i++) wsf[PK_B2 + idx * 4 + i] = fc2b[16 * T + 4 * q + i];
    } else if (j == 4472) {
        #pragma unroll
        for (int i = 0; i < 4; i++) wsf[PK_B3 + i] = fc3b[i];
    }
}

// ---------------------------------------------------------------------------
// Kernel 1: conv stack + LIF (UNCHANGED from round 12).
// ---------------------------------------------------------------------------
__device__ inline f32x2 pkfma(f32x2 a, f32x2 b, f32x2 c) {
    return __builtin_elementwise_fma(a, b, c);
}

__device__ inline void conv1_pos(float* __restrict__ c1t,
                                 const float* __restrict__ xb,
                                 const float* __restrict__ wsf,
                                 int p, int idx)
{
    float4 gb = *reinterpret_cast<const float4*>(xb + 4 * p);
    float4 ga = make_float4(0.f, 0.f, 0.f, 0.f);
    if (p > 0) ga = *reinterpret_cast<const float4*>(xb + 4 * p - 4);
    float win[7] = {ga.y, ga.z, ga.w, gb.x, gb.y, gb.z, gb.w};
    #pragma unroll
    for (int cp = 0; cp < 4; cp++) {
        f32x2 acc = *reinterpret_cast<const f32x2*>(wsf + 64 + 2 * cp);
        #pragma unroll
        for (int k = 0; k < 7; k++) {
            f32x2 wv = *reinterpret_cast<const f32x2*>(wsf + k * 8 + 2 * cp);
            f32x2 sv = {win[k], win[k]};
            acc = pkfma(wv, sv, acc);
        }
        c1t[(2 * cp + 0) * 148 + PADX(idx)] = fmaxf(acc[0], 0.f);
        c1t[(2 * cp + 1) * 148 + PADX(idx)] = fmaxf(acc[1], 0.f);
    }
}

__global__ __launch_bounds__(256) void conv_lif_kernel(
    const float* __restrict__ x,
    float* __restrict__ wsf,
    float* __restrict__ spatial_out,
    unsigned int* __restrict__ spk)
{
    __shared__ alignas(16) float smem[4812];
    float* const c1b = smem;
    float* const c3b = smem;
    float* const c2b = smem + 2376;

    const int b0  = blockIdx.x * 2;
    const int tid = threadIdx.x;
    const float* xg0 = x + (size_t)b0 * 1024;
    const float* xg1 = x + (size_t)(b0 + 1) * 1024;

    #pragma unroll
    for (int h = 0; h < 2; h++) {
        {
            const int be = tid >> 7;
            const int lp = tid & 127;
            const float* xb = be ? xg1 : xg0;
            float* c1t = c1b + be * 1188;
            const int p = 126 * h + lp;
            conv1_pos(c1t, xb, wsf, p, p + 2 - 128 * h);
            if (h == 1 && lp == 0)
                conv1_pos(c1t, xb, wsf, 254, 128);
            if (h == 0 && lp < 2) {
                #pragma unroll
                for (int ch = 0; ch < 8; ch++) c1t[ch * 148 + lp] = 0.f;
            }
        }
        __syncthreads();

        {
            const int Pl = tid & 31;
            const int be = (tid >> 5) & 1;
            const int cq = __builtin_amdgcn_readfirstlane(tid >> 6) << 2;
            const int P  = 32 * h + Pl;
            const float* wB2 = wsf + 80;
            const float* bB2 = wsf + 720;
            f32x2 a01 = *reinterpret_cast<const f32x2*>(bB2 + cq);
            f32x2 a23 = *reinterpret_cast<const f32x2*>(bB2 + cq + 2);
            const float* c1t = c1b + be * 1188;
            float* c2t = c2b + be * 1220;
            if (h == 0 && Pl == 0) {
                #pragma unroll
                for (int j = 0; j < 4; j++) c2t[(cq + j) * 76] = 0.f;
            }
            #pragma unroll
            for (int ci = 0; ci < 8; ci++) {
                const float* row = c1t + ci * 148;
                float4 va = *reinterpret_cast<const float4*>(&row[PADX(4 * Pl)]);
                float  v4 = row[PADX(4 * Pl + 4)];
                float win[5] = {va.x, va.y, va.z, va.w, v4};
                #pragma unroll
                for (int k = 0; k < 5; k++) {
                    const float* wp = wB2 + (ci * 5 + k) * 16 + cq;
                    f32x2 sv = {win[k], win[k]};
                    a01 = pkfma(*reinterpret_cast<const f32x2*>(wp),     sv, a01);
                    a23 = pkfma(*reinterpret_cast<const f32x2*>(wp + 2), sv, a23);
                }
            }
            c2t[(cq + 0) * 76 + PADX(1 + P)] = fmaxf(a01[0], 0.f);
            c2t[(cq + 1) * 76 + PADX(1 + P)] = fmaxf(a01[1], 0.f);
            c2t[(cq + 2) * 76 + PADX(1 + P)] = fmaxf(a23[0], 0.f);
            c2t[(cq + 3) * 76 + PADX(1 + P)] = fmaxf(a23[1], 0.f);
        }
        __syncthreads();
    }

    {
        const int pl  = tid & 63;
        const int be  = pl >> 5;
        const int pos = pl & 31;
        const int cb  = __builtin_amdgcn_readfirstlane(tid >> 6) << 3;
        const float* wC3 = wsf + 736;
        const float* bC3 = wsf + 2272;
        f32x2 a01 = *reinterpret_cast<const f32x2*>(bC3 + cb);
        f32x2 a23 = *reinterpret_cast<const f32x2*>(bC3 + cb + 2);
        f32x2 a45 = *reinterpret_cast<const f32x2*>(bC3 + cb + 4);
        f32x2 a67 = *reinterpret_cast<const f32x2*>(bC3 + cb + 6);
        const float* c2t = c2b + be * 1220;
        #pragma unroll
        for (int ci = 0; ci < 16; ci++) {
            const float* row = c2t + ci * 76;
            float2 vab = *reinterpret_cast<const float2*>(&row[PADX(2 * pos)]);
            float  vc  = row[PADX(2 * pos + 2)];
            float win[3] = {vab.x, vab.y, vc};
            #pragma unroll
            for (int k = 0; k < 3; k++) {
                const float* wp = wC3 + (ci * 3 + k) * 32 + cb;
                f32x2 sv = {win[k], win[k]};
                a01 = pkfma(*reinterpret_cast<const f32x2*>(wp),     sv, a01);
                a23 = pkfma(*reinterpret_cast<const f32x2*>(wp + 2), sv, a23);
                a45 = pkfma(*reinterpret_cast<const f32x2*>(wp + 4), sv, a45);
                a67 = pkfma(*reinterpret_cast<const f32x2*>(wp + 6), sv, a67);
            }
        }
        float* c3t = c3b + be * 1060;
        c3t[(cb + 0) * 33 + pos] = fmaxf(a01[0], 0.f);
        c3t[(cb + 1) * 33 + pos] = fmaxf(a01[1], 0.f);
        c3t[(cb + 2) * 33 + pos] = fmaxf(a23[0], 0.f);
        c3t[(cb + 3) * 33 + pos] = fmaxf(a23[1], 0.f);
        c3t[(cb + 4) * 33 + pos] = fmaxf(a45[0], 0.f);
        c3t[(cb + 5) * 33 + pos] = fmaxf(a45[1], 0.f);
        c3t[(cb + 6) * 33 + pos] = fmaxf(a67[0], 0.f);
        c3t[(cb + 7) * 33 + pos] = fmaxf(a67[1], 0.f);
    }
    __syncthreads();

    if (tid < 64) {
        const int be = tid >> 5, ch = tid & 31;
        const float* c3t = c3b + be * 1060;
        float s = 0.f;
        #pragma unroll
        for (int t = 0; t < 32; t++) s += c3t[ch * 33 + t];
        float sv = s * 0.03125f;
        spatial_out[(size_t)(b0 + be) * 32 + ch] = sv;
        union { __bf16 h; unsigned short u; } cv;
        cv.h = (__bf16)sv;
        ((unsigned short*)(wsf + PK_SPB))[(size_t)(b0 + be) * 32 + ch] = cv.u;

        float mem = 0.f;
        #pragma unroll
        for (int t = 0; t < 32; t++) {
            mem = __fadd_rn(__fmul_rn(0.9f, mem), c3t[ch * 33 + t]);
            bool spike = mem > 0.5f;
            mem = spike ? 0.f : mem;
            unsigned long long msk = __ballot(spike);
            if (tid == 0) {
                spk[(size_t)b0 * 32 + t]      = (unsigned int)(msk & 0xffffffffull);
                spk[(size_t)b0 * 32 + 32 + t] = (unsigned int)(msk >> 32);
            }
        }
    }
}

// ---------------------------------------------------------------------------
// Kernel 2: MFMA LSTM + FC head — 4-WAVE GATE-SPLIT. Block = 256 thr = one
// 16-batch tile; wave g owns gate g (tiles 2g,2g+1 = all 32 ch of that gate):
// 4 MFMA + 8 activations per wave per step. Acts -> LDS f32 (padded [4][16][36],
// <=2-way banks = free); combine distributed over all 256 threads (thread k
// keeps cst for fixed (row, ch, ch+16) in regs, 2 tanh, writes h bf16).
// 2 barriers/step, but 2 waves/SIMD (vs 1) and ~half the per-wave work.
// Per-(row,ch) arithmetic bit-identical to round 14 (f32 via LDS is exact).
// ---------------------------------------------------------------------------
__device__ inline float sigm(float x) {
    return __builtin_amdgcn_rcpf(1.f + __expf(-x));
}
__device__ inline float tanh_(float x) {
    return fmaf(2.f, __builtin_amdgcn_rcpf(1.f + __expf(-2.f * x)), -1.f);
}

__global__ __launch_bounds__(256, 2) void lstm_fc_mfma_kernel(
    const unsigned int* __restrict__ spk,   // [B][32]
    const float* __restrict__ wsf,          // prepacked weights + spatial_bf
    float* __restrict__ out0,               // [B][4]
    float* __restrict__ hlast_out)          // [B][32]
{
    const int ltid = threadIdx.x;
    const int l    = ltid & 63;
    const int g    = ltid >> 6;             // wave = gate (0=i,1=f,2=g,3=o)
    const int row  = l & 15;
    const int q    = l >> 4;
    const int base = blockIdx.x * 16;

    __shared__ unsigned int mlds[512];           // [t][16]
    __shared__ alignas(16) __bf16 hdb[640];      // h: [16][40] (ch at +0..31)
    __shared__ alignas(16) float  actb[2304];    // acts: [4][16][36]
    __shared__ alignas(16) __bf16 zlds[1152];    // fc1 out: [16][72]

    for (int i = ltid; i < 512; i += 256) {
        int j = i >> 5, t = i & 31;
        mlds[t * 16 + j] = spk[(size_t)(base + j) * 32 + t];
    }
    for (int i = ltid; i < 640; i += 256) hdb[i] = (__bf16)0.f;

    union bc { u32x4 u; bf16x8 v; };
    const u32x4* wihp = (const u32x4*)(wsf + PK_WIH);
    const u32x4* whhp = (const u32x4*)(wsf + PK_WHH);

    // wave g: tiles T0=2g (ch 0-15), T1=2g+1 (ch 16-31) of gate g
    const int T0 = 2 * g, T1 = 2 * g + 1;
    bf16x8 wih0, wih1, whh0, whh1;
    { bc a; a.u = wihp[T0 * 64 + l]; wih0 = a.v; }
    { bc a; a.u = wihp[T1 * 64 + l]; wih1 = a.v; }
    { bc a; a.u = whhp[T0 * 64 + l]; whh0 = a.v; }
    { bc a; a.u = whhp[T1 * 64 + l]; whh1 = a.v; }
    f32x4 bfr0 = *reinterpret_cast<const f32x4*>(wsf + PK_BFR + (T0 * 4 + q) * 4);
    f32x4 bfr1 = *reinterpret_cast<const f32x4*>(wsf + PK_BFR + (T1 * 4 + q) * 4);

    // activation: tanh for gate 2, sigmoid otherwise (wave-uniform params)
    const float as = (g == 2) ? 2.f : 1.f;
    const float am = (g == 2) ? 2.f : 1.f;
    const float ac = (g == 2) ? -1.f : 0.f;

    // combine-thread fixed assignment: (crow, ch0=cci, ch1=16+cci)
    const int crow = ltid & 15, cci = ltid >> 4;   // cci 0..15
    float cst0 = 0.f, cst1 = 0.f, h0 = 0.f, h1 = 0.f;

    __syncthreads();                        // mlds + hdb zero ready

    #pragma unroll 1
    for (int t = 0; t < 32; t++) {
        unsigned int m  = mlds[t * 16 + row];
        unsigned int by = (m >> (q * 8)) & 0xFFu;
        union { bf16x8 v; unsigned int u[4]; } a1;
        a1.u[0] = ((by & 1u)        * 0x3F80u) | (((by >> 1) & 1u) * 0x3F800000u);
        a1.u[1] = (((by >> 2) & 1u) * 0x3F80u) | (((by >> 3) & 1u) * 0x3F800000u);
        a1.u[2] = (((by >> 4) & 1u) * 0x3F80u) | (((by >> 5) & 1u) * 0x3F800000u);
        a1.u[3] = (((by >> 6) & 1u) * 0x3F80u) | (((by >> 7) & 1u) * 0x3F800000u);
        bf16x8 a2 = *reinterpret_cast<bf16x8*>(&hdb[row * 40 + q * 8]);

        f32x4 acc0 = __builtin_amdgcn_mfma_f32_16x16x32_bf16(wih0, a1.v, bfr0, 0, 0, 0);
        acc0       = __builtin_amdgcn_mfma_f32_16x16x32_bf16(whh0, a2,   acc0, 0, 0, 0);
        f32x4 acc1 = __builtin_amdgcn_mfma_f32_16x16x32_bf16(wih1, a1.v, bfr1, 0, 0, 0);
        acc1       = __builtin_amdgcn_mfma_f32_16x16x32_bf16(whh1, a2,   acc1, 0, 0, 0);

        f32x4 e0, e1;
        #pragma unroll
        for (int j = 0; j < 4; j++) {
            e0[j] = fmaf(am, sigm(as * acc0[j]), ac);
            e1[j] = fmaf(am, sigm(as * acc1[j]), ac);
        }
        *reinterpret_cast<f32x4*>(&actb[g * 576 + row * 36 + 4 * q])      = e0;
        *reinterpret_cast<f32x4*>(&actb[g * 576 + row * 36 + 16 + 4 * q]) = e1;
        __syncthreads();                    // acts visible

        // combine: thread owns (crow, cci) and (crow, 16+cci)
        {
            float iv0 = actb[0 * 576 + crow * 36 + cci];
            float fv0 = actb[1 * 576 + crow * 36 + cci];
            float gv0 = actb[2 * 576 + crow * 36 + cci];
            float ov0 = actb[3 * 576 + crow * 36 + cci];
            float iv1 = actb[0 * 576 + crow * 36 + 16 + cci];
            float fv1 = actb[1 * 576 + crow * 36 + 16 + cci];
            float gv1 = actb[2 * 576 + crow * 36 + 16 + cci];
            float ov1 = actb[3 * 576 + crow * 36 + 16 + cci];
            cst0 = fmaf(fv0, cst0, iv0 * gv0);
            h0   = ov0 * tanh_(cst0);
            cst1 = fmaf(fv1, cst1, iv1 * gv1);
            h1   = ov1 * tanh_(cst1);
            hdb[crow * 40 + cci]      = (__bf16)h0;
            hdb[crow * 40 + 16 + cci] = (__bf16)h1;
        }
        __syncthreads();                    // h visible for next step
    }

    // ---- h_last output (fp32, from combine-thread registers) ----
    hlast_out[(size_t)(base + crow) * 32 + cci]      = h0;
    hlast_out[(size_t)(base + crow) * 32 + 16 + cci] = h1;

    // ---- FC head: fc1's 4 tiles map 1:1 onto the 4 waves ----
    bf16x8 hf = *reinterpret_cast<bf16x8*>(&hdb[row * 40 + 8 * q]);
    bf16x8 spf;
    {
        bc s_;
        s_.u = *reinterpret_cast<const u32x4*>(
            (const unsigned short*)(wsf + PK_SPB) + (size_t)(base + row) * 32 + 8 * q);
        spf = s_.v;
    }

    const u32x4* fc1p = (const u32x4*)(wsf + PK_FC1);
    {
        const int T = g;
        bc x0_, x1_;
        x0_.u = fc1p[(T * 2 + 0) * 64 + l];
        x1_.u = fc1p[(T * 2 + 1) * 64 + l];
        f32x4 c = *reinterpret_cast<const f32x4*>(wsf + PK_B1 + (T * 4 + q) * 4);
        f32x4 a = __builtin_amdgcn_mfma_f32_16x16x32_bf16(x0_.v, hf,  c, 0, 0, 0);
        a       = __builtin_amdgcn_mfma_f32_16x16x32_bf16(x1_.v, spf, a, 0, 0, 0);
        bf16x4 zv;
        #pragma unroll
        for (int i = 0; i < 4; i++) zv[i] = (__bf16)fmaxf(a[i], 0.f);
        *reinterpret_cast<bf16x4*>(&zlds[row * 72 + 16 * T + 4 * q]) = zv;
    }
    __syncthreads();
    bf16x8 z1f0 = *reinterpret_cast<bf16x8*>(&zlds[row * 72 + 8 * q]);
    bf16x8 z1f1 = *reinterpret_cast<bf16x8*>(&zlds[row * 72 + 32 + 8 * q]);

    // fc2: 2 tiles on waves 0,1; result into actb reused as bf16 [16][40]
    __bf16* z2b = (__bf16*)actb;
    const u32x4* fc2p = (const u32x4*)(wsf + PK_FC2);
    if (g < 2) {
        const int T = g;
        bc x0_, x1_;
        x0_.u = fc2p[(T * 2 + 0) * 64 + l];
        x1_.u = fc2p[(T * 2 + 1) * 64 + l];
        f32x4 c = *reinterpret_cast<const f32x4*>(wsf + PK_B2 + (T * 4 + q) * 4);
        f32x4 a = __builtin_amdgcn_mfma_f32_16x16x32_bf16(x0_.v, z1f0, c, 0, 0, 0);
        a       = __builtin_amdgcn_mfma_f32_16x16x32_bf16(x1_.v, z1f1, a, 0, 0, 0);
        bf16x4 zv;
        #pragma unroll
        for (int i = 0; i < 4; i++) zv[i] = (__bf16)fmaxf(a[i], 0.f);
        *reinterpret_cast<bf16x4*>(&z2b[row * 40 + 16 * T + 4 * q]) = zv;
    }
    __syncthreads();

    // fc3: wave 0 only
    if (g == 0) {
        bf16x8 z2f = *reinterpret_cast<bf16x8*>(&z2b[row * 40 + 8 * q]);
        bc x3_;
        x3_.u = ((const u32x4*)(wsf + PK_FC3))[l];
        f32x4 c = *reinterpret_cast<const f32x4*>(wsf + PK_B3);
        f32x4 o = __builtin_amdgcn_mfma_f32_16x16x32_bf16(x3_.v, z2f, c, 0, 0, 0);
        if (l < 16)
            *reinterpret_cast<f32x4*>(out0 + (size_t)(base + row) * 4) = o;
    }
}

// ---------------------------------------------------------------------------
extern "C" void kernel_launch(void* const* d_in, const int* in_sizes, int n_in,
                              void* d_out, int out_size, void* d_ws, size_t ws_size,
                              hipStream_t stream) {
    const float* x    = (const float*)d_in[0];
    const float* w1   = (const float*)d_in[1];
    const float* b1   = (const float*)d_in[2];
    const float* g1   = (const float*)d_in[3];
    const float* be1  = (const float*)d_in[4];
    const float* m1   = (const float*)d_in[5];
    const float* v1   = (const float*)d_in[6];
    const float* w2   = (const float*)d_in[7];
    const float* b2   = (const float*)d_in[8];
    const float* g2   = (const float*)d_in[9];
    const float* be2  = (const float*)d_in[10];
    const float* m2   = (const float*)d_in[11];
    const float* v2   = (const float*)d_in[12];
    const float* w3   = (const float*)d_in[13];
    const float* b3   = (const float*)d_in[14];
    const float* g3   = (const float*)d_in[15];
    const float* be3  = (const float*)d_in[16];
    const float* m3   = (const float*)d_in[17];
    const float* v3   = (const float*)d_in[18];
    const float* w_ih = (const float*)d_in[19];
    const float* w_hh = (const float*)d_in[20];
    const float* b_ih = (const float*)d_in[21];
    const float* b_hh = (const float*)d_in[22];
    const float* fc1w = (const float*)d_in[23];
    const float* fc1b = (const float*)d_in[24];
    const float* fc2w = (const float*)d_in[25];
    const float* fc2b = (const float*)d_in[26];
    const float* fc3w = (const float*)d_in[27];
    const float* fc3b = (const float*)d_in[28];

    float* out0    = (float*)d_out;                 // [8192][4]
    float* spatial = out0 + (size_t)NB * 4;         // [8192][32]
    float* hlast   = spatial + (size_t)NB * 32;     // [8192][32]
    unsigned int* spk = (unsigned int*)d_ws;        // [8192][32] bitmasks
    float* wsf = (float*)d_ws + WSF_OFF;            // folded + prepacked weights

    hipLaunchKernelGGL(fold_kernel, dim3(18), dim3(256), 0, stream,
                       w1, b1, g1, be1, m1, v1,
                       w2, b2, g2, be2, m2, v2,
                       w3, b3, g3, be3, m3, v3,
                       w_ih, w_hh, b_ih, b_hh,
                       fc1w, fc1b, fc2w, fc2b, fc3w, fc3b, wsf);

    hipLaunchKernelGGL(conv_lif_kernel, dim3(NB / 2), dim3(256), 0, stream,
                       x, wsf, spatial, spk);

    hipLaunchKernelGGL(lstm_fc_mfma_kernel, dim3(NB / 16), dim3(256), 0, stream,
                       spk, wsf, out0, hlast);
}